// Round 3
// baseline (74.458 us; speedup 1.0000x reference)
//
#include <hip/hip_runtime.h>
#include <hip/hip_bf16.h>
#include <stdint.h>

// ---------------------------------------------------------------------------
// MultiScaleAttention: x[4,128,4096] -> 3x conv1x1+PReLU -> attention -> out
//   Q = e1^T * log2e [n][s][64], K = e2^T [n][s][64] (bf16)
//   V^T = asm [n][128][4096] (bf16, natural conv layout)
//   attn: S^T = K Q^T (mfma 32x32x16, swapped), p = exp2(S^T) unnormalized,
//   O^T[dv][q] = V^T P^T; num (bf16) + den (f32) partials over 8 kv-splits.
//   Each wave owns 64 q-cols (2 MFMA col-sets) -> halves LDS reads per FLOP.
// ---------------------------------------------------------------------------

typedef float   f32x16 __attribute__((ext_vector_type(16)));
typedef __bf16  bf16x8 __attribute__((ext_vector_type(8)));
typedef __bf16  bf16x2 __attribute__((ext_vector_type(2)));
typedef unsigned int u32x4 __attribute__((ext_vector_type(4)));
typedef unsigned int u32x2 __attribute__((ext_vector_type(2)));

#define L2E 1.4426950408889634f

// workspace layout (bytes); ws_size ~268MB (poison fill = 262144KB)
#define Q_OFF   (0u)
#define K_OFF   (2u << 20)
#define V_OFF   (4u << 20)
#define DEN_OFF (8u << 20)                    // [4][16][8][256] f32 = 512KB
#define XTH_OFF ((8u << 20) + (1u << 19))     // 8.5MB: xT hi bf16 [n][s][128] (4MB)
#define XTL_OFF (XTH_OFF + (4u << 20))        // xT lo (4MB)
#define WH_OFF  (XTL_OFF + (4u << 20))        // W hi bf16 [256][128] (64KB)
#define WL_OFF  (WH_OFF + (1u << 16))
#define OP_OFF  XTH_OFF                       // num bf16 [4][16][8][128][256] = 33.5MB
                                              // aliases xT/W (dead after conv)

__device__ inline unsigned short f2bf(float f) {
  unsigned u = __builtin_bit_cast(unsigned, f);
  return (unsigned short)((u + 0x7FFFu + ((u >> 16) & 1u)) >> 16);  // RNE
}
__device__ inline float bf2f(unsigned short h) {
  unsigned u = ((unsigned)h) << 16;
  return __builtin_bit_cast(float, u);
}

__device__ inline void gld_lds16(const void* g, void* l) {
  __builtin_amdgcn_global_load_lds(
      (const __attribute__((address_space(1))) unsigned*)g,
      (__attribute__((address_space(3))) unsigned*)l, 16, 0, 0);
}

// --------------------------- kernel 0: transpose x -------------------------
// x[n][128][4096] f32 -> xT hi/lo bf16 [n][4096][128]
__global__ __launch_bounds__(256) void transpose_kernel(
    const float* __restrict__ x, char* __restrict__ ws) {
  int bid = blockIdx.x;                 // 512 = 4n * 2ct * 64st
  int n = bid >> 7, rem = bid & 127;
  int c0 = (rem >> 6) * 64, s0 = (rem & 63) * 64;
  int tid = threadIdx.x;
  __shared__ float tl[64][65];
  const float* xb = x + (size_t)n * 128 * 4096;
#pragma unroll
  for (int i = 0; i < 16; ++i) {
    int cl = (tid >> 6) * 16 + i;
    tl[cl][tid & 63] = xb[(size_t)(c0 + cl) * 4096 + s0 + (tid & 63)];
  }
  __syncthreads();
  char* XH = ws + XTH_OFF + (size_t)n * (4096 * 256);
  char* XL = ws + XTL_OFF + (size_t)n * (4096 * 256);
#pragma unroll
  for (int it = 0; it < 2; ++it) {
    int sl = (tid >> 3) + it * 32;
    int c8 = (tid & 7) * 8;
    unsigned short uh[8], ul[8];
#pragma unroll
    for (int i = 0; i < 8; ++i) {
      float v = tl[c8 + i][sl];
      unsigned short h = f2bf(v);
      uh[i] = h;
      ul[i] = f2bf(v - bf2f(h));
    }
    u32x4 ph, pl;
    ph.x = ((unsigned)uh[1] << 16) | uh[0]; ph.y = ((unsigned)uh[3] << 16) | uh[2];
    ph.z = ((unsigned)uh[5] << 16) | uh[4]; ph.w = ((unsigned)uh[7] << 16) | uh[6];
    pl.x = ((unsigned)ul[1] << 16) | ul[0]; pl.y = ((unsigned)ul[3] << 16) | ul[2];
    pl.z = ((unsigned)ul[5] << 16) | ul[4]; pl.w = ((unsigned)ul[7] << 16) | ul[6];
    size_t off = (size_t)(s0 + sl) * 256 + c0 * 2 + (tid & 7) * 16;
    *(u32x4*)(XH + off) = ph;
    *(u32x4*)(XL + off) = pl;
  }
}

// --------------------------- kernel 1: cast weights ------------------------
__global__ void wcast_kernel(const float* __restrict__ w1, const float* __restrict__ w2,
                             const float* __restrict__ wa, char* __restrict__ ws) {
  int idx = blockIdx.x * 256 + threadIdx.x;   // 32 blocks
  unsigned short* WH = (unsigned short*)(ws + WH_OFF);
  unsigned short* WL = (unsigned short*)(ws + WL_OFF);
#pragma unroll
  for (int r = 0; r < 4; ++r) {
    int i = r * 8192 + idx;                   // 0..32767
    int oc = i >> 7, c = i & 127;
    float v = oc < 64 ? w1[oc * 128 + c]
            : (oc < 128 ? w2[(oc - 64) * 128 + c] : wa[(oc - 128) * 128 + c]);
    unsigned short h = f2bf(v);
    WH[i] = h;
    WL[i] = f2bf(v - bf2f(h));
  }
}

// ---------------- kernel 2: conv1x1 + bias + PReLU -> Q,K,V -----------------
// split-bf16 mfma GEMM: Y[256][32s] per block; waves: 0->Q(*L2E), 1->K, 2,3->V.
__global__ __launch_bounds__(256) void conv_kernel(
    char* __restrict__ ws,
    const float* __restrict__ b1, const float* __restrict__ a1,
    const float* __restrict__ b2, const float* __restrict__ a2,
    const float* __restrict__ ba, const float* __restrict__ aa) {
  int bid = blockIdx.x;                 // 512 = 4n * 128 s-tiles
  int n = bid >> 7, st = bid & 127;
  int sb = st * 32;
  int tid = threadIdx.x;
  int wid = tid >> 6, lane = tid & 63, l31 = lane & 31, hi = lane >> 5;
  const char* XH = ws + XTH_OFF + (size_t)n * (4096 * 256);
  const char* XL = ws + XTL_OFF + (size_t)n * (4096 * 256);
  const char* WH = ws + WH_OFF;
  const char* WL = ws + WL_OFF;
  int oc0 = wid * 64;

  f32x16 acc[2];
  acc[0] = 0.f; acc[1] = 0.f;
#pragma unroll
  for (int c0 = 0; c0 < 8; ++c0) {
    size_t xo = (size_t)(sb + l31) * 256 + c0 * 32 + hi * 16;
    bf16x8 xh = *(const bf16x8*)(XH + xo);
    bf16x8 xl = *(const bf16x8*)(XL + xo);
#pragma unroll
    for (int mb = 0; mb < 2; ++mb) {
      size_t wo = (size_t)(oc0 + mb * 32 + l31) * 256 + c0 * 32 + hi * 16;
      bf16x8 wh = *(const bf16x8*)(WH + wo);
      bf16x8 wl = *(const bf16x8*)(WL + wo);
      acc[mb] = __builtin_amdgcn_mfma_f32_32x32x16_bf16(wh, xh, acc[mb], 0, 0, 0);
      acc[mb] = __builtin_amdgcn_mfma_f32_32x32x16_bf16(wh, xl, acc[mb], 0, 0, 0);
      acc[mb] = __builtin_amdgcn_mfma_f32_32x32x16_bf16(wl, xh, acc[mb], 0, 0, 0);
    }
  }

  __shared__ float tl[2][64][33];
  char* Qw = ws + Q_OFF + (size_t)n * (4096 * 64 * 2);
  char* Kw = ws + K_OFF + (size_t)n * (4096 * 64 * 2);
  unsigned short* Vw = (unsigned short*)(ws + V_OFF) + (size_t)n * 128 * 4096;

  if (wid < 2) {
    const float* bb = wid ? b2 : b1;
    float slope = wid ? a2[0] : a1[0];
    float scl = wid ? 1.0f : L2E;       // fold softmax log2e into Q
#pragma unroll
    for (int mb = 0; mb < 2; ++mb)
#pragma unroll
      for (int reg = 0; reg < 16; ++reg) {
        int row = mb * 32 + (reg & 3) + 8 * (reg >> 2) + 4 * hi;
        float y = acc[mb][reg] + bb[row];
        y = fmaxf(y, 0.f) + slope * fminf(y, 0.f);
        tl[wid][row][l31] = y * scl;
      }
  } else {
    float slope = aa[0];
#pragma unroll
    for (int mb = 0; mb < 2; ++mb)
#pragma unroll
      for (int reg = 0; reg < 16; ++reg) {
        int dv = (wid - 2) * 64 + mb * 32 + (reg & 3) + 8 * (reg >> 2) + 4 * hi;
        float y = acc[mb][reg] + ba[dv];
        y = fmaxf(y, 0.f) + slope * fminf(y, 0.f);
        Vw[(size_t)dv * 4096 + sb + l31] = f2bf(y);
      }
  }
  __syncthreads();
  if (wid < 2) {   // LDS-transposed, coalesced bf16 store of Q/K [s][64]
    char* Og = wid ? Kw : Qw;
#pragma unroll
    for (int it = 0; it < 4; ++it) {
      int sl = (lane >> 3) + it * 8;
      unsigned short u[8];
#pragma unroll
      for (int i = 0; i < 8; ++i) u[i] = f2bf(tl[wid][(lane & 7) * 8 + i][sl]);
      u32x4 pv;
      pv.x = ((unsigned)u[1] << 16) | u[0]; pv.y = ((unsigned)u[3] << 16) | u[2];
      pv.z = ((unsigned)u[5] << 16) | u[4]; pv.w = ((unsigned)u[7] << 16) | u[6];
      *(u32x4*)(Og + (size_t)(sb + sl) * 128 + (lane & 7) * 16) = pv;
    }
  }
}

// --------------------------- kernel 3: flash attention ----------------------
// 512 blocks: bid = qt*32 + batch*8 + split  (split in low 3 bits -> same XCD
// for all blocks sharing a KV slice). Block = 4 waves * 64 q = 256 q,
// kv range = split*512 .. +512 (8 tiles of 64). 2 blocks/CU.
__global__ __launch_bounds__(256, 2) void attn_kernel(char* __restrict__ ws) {
  int bid = blockIdx.x;
  int qt = bid >> 5;
  int batch = (bid >> 3) & 3;
  int split = bid & 7;
  int tid = threadIdx.x;
  int wid = tid >> 6, lane = tid & 63, l31 = lane & 31, hi = lane >> 5;

  const char* Qb = ws + Q_OFF + (size_t)batch * (4096 * 64 * 2);
  const char* Kb = ws + K_OFF + (size_t)batch * (4096 * 64 * 2);
  const char* Vb = ws + V_OFF + (size_t)batch * (128 * 4096 * 2);

  __shared__ char kbuf[2][64 * 128];    // [k][64d] bf16, XOR-swizzled slots
  __shared__ char vbuf[2][128 * 128];   // [dv][64k] bf16, XOR-swizzled slots

  int q0 = qt * 256 + wid * 64;

  bf16x8 qf[2][4];                      // Q B-frags for 2 q-sets
#pragma unroll
  for (int qs = 0; qs < 2; ++qs)
#pragma unroll
    for (int d0 = 0; d0 < 4; ++d0)
      qf[qs][d0] = *(const bf16x8*)(Qb + (size_t)(q0 + qs * 32 + l31) * 128 +
                                    d0 * 32 + hi * 16);

  f32x16 oacc[2][4];
#pragma unroll
  for (int qs = 0; qs < 2; ++qs)
#pragma unroll
    for (int i = 0; i < 4; ++i) oacc[qs][i] = 0.f;
  float den[2] = {0.f, 0.f};

  int t0 = split * 8;                   // absolute 64-kv tile index base

  auto stage = [&](int b, int tile) {
    int kv0 = tile * 64;
#pragma unroll
    for (int i = 0; i < 2; ++i) {       // K: 8KB
      int base = wid * 2048 + i * 1024;
      int L = base + (lane << 4);
      int r = L >> 7, sl = (L >> 4) & 7;
      const char* src = Kb + (size_t)(kv0 + r) * 128 + ((sl ^ (r & 7)) << 4);
      gld_lds16(src, &kbuf[b][base]);
    }
#pragma unroll
    for (int i = 0; i < 4; ++i) {       // V: 16KB
      int base = wid * 4096 + i * 1024;
      int L = base + (lane << 4);
      int r = L >> 7, sl = (L >> 4) & 7;
      const char* src = Vb + (size_t)r * 8192 + kv0 * 2 + ((sl ^ (r & 7)) << 4);
      gld_lds16(src, &vbuf[b][base]);
    }
  };

  stage(0, t0);
  __syncthreads();
  int cur = 0;

  for (int t = 0; t < 8; ++t) {
    if (t + 1 < 8) stage(cur ^ 1, t0 + t + 1);

    unsigned pk[2][2][8];               // packed bf16 P for both q-sets
#pragma unroll
    for (int qs = 0; qs < 2; ++qs) {
      // S^T[k][q] = K·Q^T (q = qs*32 + l31; k = 32kb + (reg&3)+8(reg>>2)+4hi)
      f32x16 sacc[2];
      sacc[0] = 0.f; sacc[1] = 0.f;
#pragma unroll
      for (int kb = 0; kb < 2; ++kb) {
        int r = kb * 32 + l31;
#pragma unroll
        for (int d0 = 0; d0 < 4; ++d0) {
          bf16x8 kf = *(const bf16x8*)(
              &kbuf[cur][r * 128 + (((d0 * 2 + hi) ^ (r & 7)) << 4)]);
          sacc[kb] = __builtin_amdgcn_mfma_f32_32x32x16_bf16(kf, qf[qs][d0],
                                                             sacc[kb], 0, 0, 0);
        }
      }
      // p = exp2(s) (Q pre-scaled by log2e); no shift (unnormalized)
#pragma unroll
      for (int kb = 0; kb < 2; ++kb)
#pragma unroll
        for (int m = 0; m < 8; ++m) {
          float e0 = __builtin_amdgcn_exp2f(sacc[kb][2 * m]);
          float e1 = __builtin_amdgcn_exp2f(sacc[kb][2 * m + 1]);
          den[qs] += e0 + e1;
          bf16x2 bp = { (__bf16)e0, (__bf16)e1 };
          pk[qs][kb][m] = __builtin_bit_cast(unsigned, bp);
        }
    }

    // PV: O^T[dv][q] += V^T · P^T ; vf shared across both q-sets
#pragma unroll
    for (int kc = 0; kc < 4; ++kc) {
      const int kb = kc >> 1, bs = (kc & 1) * 4;
      bf16x8 pf[2];
#pragma unroll
      for (int qs = 0; qs < 2; ++qs) {
        u32x2 r0 = __builtin_amdgcn_permlane32_swap(pk[qs][kb][bs + 0],
                                                    pk[qs][kb][bs + 2], false, false);
        u32x2 r1 = __builtin_amdgcn_permlane32_swap(pk[qs][kb][bs + 1],
                                                    pk[qs][kb][bs + 3], false, false);
        u32x4 pu = {r0.x, r1.x, r0.y, r1.y};
        pf[qs] = __builtin_bit_cast(bf16x8, pu);
      }
#pragma unroll
      for (int dvb = 0; dvb < 4; ++dvb) {
        int r = dvb * 32 + l31;
        bf16x8 vf = *(const bf16x8*)(
            &vbuf[cur][r * 128 + (((kc * 2 + hi) ^ (r & 7)) << 4)]);
        oacc[0][dvb] = __builtin_amdgcn_mfma_f32_32x32x16_bf16(vf, pf[0],
                                                               oacc[0][dvb], 0, 0, 0);
        oacc[1][dvb] = __builtin_amdgcn_mfma_f32_32x32x16_bf16(vf, pf[1],
                                                               oacc[1][dvb], 0, 0, 0);
      }
    }

    __syncthreads();
    cur ^= 1;
  }

  // write numerator partials (bf16) + denominator (f32)
  unsigned short* OPu = (unsigned short*)(ws + OP_OFF) +
                        (size_t)((batch * 16 + qt) * 8 + split) * 128 * 256;
#pragma unroll
  for (int qs = 0; qs < 2; ++qs) {
    int qloc = wid * 64 + qs * 32 + l31;
#pragma unroll
    for (int dvb = 0; dvb < 4; ++dvb)
#pragma unroll
      for (int reg = 0; reg < 16; ++reg) {
        int dv = dvb * 32 + (reg & 3) + 8 * (reg >> 2) + 4 * hi;
        OPu[dv * 256 + qloc] = f2bf(oacc[qs][dvb][reg]);
      }
    float dtot = den[qs] + __shfl_xor(den[qs], 32, 64);
    if (hi == 0) {
      float* DEN = (float*)(ws + DEN_OFF) +
                   (size_t)((batch * 16 + qt) * 8 + split) * 256;
      DEN[qloc] = dtot;
    }
  }
}

// --------------------------- kernel 4: combine splits -----------------------
__global__ __launch_bounds__(256) void combine_kernel(const char* __restrict__ ws,
                                                      float* __restrict__ out) {
  int idx = blockIdx.x * 256 + threadIdx.x;  // 2^21 outputs [n][c][s]
  int n = idx >> 19;
  int dv = (idx >> 12) & 127;
  int s = idx & 4095;
  int qt = s >> 8, ql = s & 255;
  const unsigned short* OPu = (const unsigned short*)(ws + OP_OFF);
  const float* DEN = (const float*)(ws + DEN_OFF);
  size_t pb = (size_t)((n * 16 + qt) * 8);
  float num = 0.f, den = 0.f;
#pragma unroll
  for (int h = 0; h < 8; ++h) {
    num += bf2f(OPu[(pb + h) * 128 * 256 + (size_t)dv * 256 + ql]);
    den += DEN[(pb + h) * 256 + ql];
  }
  out[idx] = num / den;
}

// ---------------------------------------------------------------------------
extern "C" void kernel_launch(void* const* d_in, const int* in_sizes, int n_in,
                              void* d_out, int out_size, void* d_ws, size_t ws_size,
                              hipStream_t stream) {
  (void)in_sizes; (void)n_in; (void)out_size; (void)ws_size;
  const float* x  = (const float*)d_in[0];
  const float* w1 = (const float*)d_in[1];
  const float* b1 = (const float*)d_in[2];
  const float* a1 = (const float*)d_in[3];
  const float* w2 = (const float*)d_in[4];
  const float* b2 = (const float*)d_in[5];
  const float* a2 = (const float*)d_in[6];
  const float* wa = (const float*)d_in[7];
  const float* ba = (const float*)d_in[8];
  const float* aa = (const float*)d_in[9];
  char* ws = (char*)d_ws;
  float* out = (float*)d_out;

  transpose_kernel<<<dim3(512), dim3(256), 0, stream>>>(x, ws);
  wcast_kernel<<<dim3(32), dim3(256), 0, stream>>>(w1, w2, wa, ws);
  conv_kernel<<<dim3(512), dim3(256), 0, stream>>>(ws, b1, a1, b2, a2, ba, aa);
  attn_kernel<<<dim3(512), dim3(256), 0, stream>>>(ws);
  combine_kernel<<<dim3(8192), dim3(256), 0, stream>>>(ws, out);
}

// Round 4
// 64.646 us; speedup vs baseline: 1.1518x; 1.1518x over previous
//
#include <hip/hip_runtime.h>
#include <hip/hip_bf16.h>
#include <stdint.h>

// ---------------------------------------------------------------------------
// MultiScaleAttention: x[4,128,4096] -> 3x conv1x1+PReLU -> attention -> out
//   conv (fused transpose): Q = e1^T * log2e [n][s][64], K = e2^T [n][s][64],
//   V^T = asm [n][128][4096] (bf16). Split-bf16 (hi+lo) MFMA for fp32 accuracy.
//   attn: S^T = K Q^T (mfma 32x32x16, swapped), p = exp2(S^T) unnormalized,
//   O^T[dv][q] = V^T P^T; num (bf16) + den (f32) partials over 8 kv-splits.
//   Grid 1024, 3 blocks/CU (LDS 48KB) for latency hiding; split pinned to XCD.
// ---------------------------------------------------------------------------

typedef float   f32x16 __attribute__((ext_vector_type(16)));
typedef __bf16  bf16x8 __attribute__((ext_vector_type(8)));
typedef __bf16  bf16x2 __attribute__((ext_vector_type(2)));
typedef unsigned int u32x4 __attribute__((ext_vector_type(4)));
typedef unsigned int u32x2 __attribute__((ext_vector_type(2)));

#define L2E 1.4426950408889634f

// workspace layout (bytes); ws_size ~268MB
#define Q_OFF   (0u)                          // [4][4096][64] bf16 = 2MB
#define K_OFF   (2u << 20)                    // [4][4096][64] bf16 = 2MB
#define V_OFF   (4u << 20)                    // [4][128][4096] bf16 = 4MB
#define DEN_OFF (8u << 20)                    // [4][32][8][128] f32 = 512KB
#define WH_OFF  ((8u << 20) + (1u << 19))     // W hi bf16 [256][128] = 64KB
#define WL_OFF  (WH_OFF + (1u << 16))
#define OP_OFF  (9u << 20)                    // num bf16 [4][32][8][128][128] = 33.5MB

__device__ inline unsigned short f2bf(float f) {
  unsigned u = __builtin_bit_cast(unsigned, f);
  return (unsigned short)((u + 0x7FFFu + ((u >> 16) & 1u)) >> 16);  // RNE
}
__device__ inline float bf2f(unsigned short h) {
  unsigned u = ((unsigned)h) << 16;
  return __builtin_bit_cast(float, u);
}

__device__ inline void gld_lds16(const void* g, void* l) {
  __builtin_amdgcn_global_load_lds(
      (const __attribute__((address_space(1))) unsigned*)g,
      (__attribute__((address_space(3))) unsigned*)l, 16, 0, 0);
}

// --------------------------- kernel 0: cast weights ------------------------
__global__ void wcast_kernel(const float* __restrict__ w1, const float* __restrict__ w2,
                             const float* __restrict__ wa, char* __restrict__ ws) {
  int idx = blockIdx.x * 256 + threadIdx.x;   // 32 blocks
  unsigned short* WH = (unsigned short*)(ws + WH_OFF);
  unsigned short* WL = (unsigned short*)(ws + WL_OFF);
#pragma unroll
  for (int r = 0; r < 4; ++r) {
    int i = r * 8192 + idx;                   // 0..32767
    int oc = i >> 7, c = i & 127;
    float v = oc < 64 ? w1[oc * 128 + c]
            : (oc < 128 ? w2[(oc - 64) * 128 + c] : wa[(oc - 128) * 128 + c]);
    unsigned short h = f2bf(v);
    WH[i] = h;
    WL[i] = f2bf(v - bf2f(h));
  }
}

// ------- kernel 1: conv1x1 + bias + PReLU -> Q,K,V (fused x transpose) ------
// 512 blocks = 4n * 128 s-tiles(32). Waves: 0->Q(*L2E), 1->K, 2,3->V.
// x tile staged in LDS [128c][36 pad] f32; B-frags built in-register (hi/lo).
__global__ __launch_bounds__(256) void conv_kernel(
    const float* __restrict__ x, char* __restrict__ ws,
    const float* __restrict__ b1, const float* __restrict__ a1,
    const float* __restrict__ b2, const float* __restrict__ a2,
    const float* __restrict__ ba, const float* __restrict__ aa) {
  int bid = blockIdx.x;
  int n = bid >> 7, st = bid & 127;
  int sb = st * 32;
  int tid = threadIdx.x;
  int wid = tid >> 6, lane = tid & 63, l31 = lane & 31, hi = lane >> 5;

  __shared__ float xl[128][36];         // stride 36 words: b128-aligned, 2-way banks
  __shared__ float tl[2][64][33];

  const float* xb = x + (size_t)n * 128 * 4096;
#pragma unroll
  for (int it = 0; it < 4; ++it) {      // load 128x32 f32 tile, transposed store
    int flat4 = tid + 256 * it;
    int c = flat4 >> 3, s4 = flat4 & 7;
    float4 v = *(const float4*)(xb + (size_t)c * 4096 + sb + s4 * 4);
    *(float4*)&xl[c][s4 * 4] = v;
  }
  __syncthreads();

  const char* WH = ws + WH_OFF;
  const char* WL = ws + WL_OFF;
  int oc0 = wid * 64;

  f32x16 acc[2];
  acc[0] = 0.f; acc[1] = 0.f;
#pragma unroll
  for (int c0 = 0; c0 < 8; ++c0) {
    // B-frag: x^T[s=l31][k = c0*16 + hi*8 + j], hi/lo split in-register
    __bf16 eh[8], el[8];
#pragma unroll
    for (int j = 0; j < 8; ++j) {
      float v = xl[c0 * 16 + hi * 8 + j][l31];
      __bf16 h = (__bf16)v;
      eh[j] = h;
      el[j] = (__bf16)(v - (float)h);
    }
    bf16x8 xh = {eh[0], eh[1], eh[2], eh[3], eh[4], eh[5], eh[6], eh[7]};
    bf16x8 xlo = {el[0], el[1], el[2], el[3], el[4], el[5], el[6], el[7]};
#pragma unroll
    for (int mb = 0; mb < 2; ++mb) {
      size_t wo = (size_t)(oc0 + mb * 32 + l31) * 256 + c0 * 32 + hi * 16;
      bf16x8 wh = *(const bf16x8*)(WH + wo);
      bf16x8 wl = *(const bf16x8*)(WL + wo);
      acc[mb] = __builtin_amdgcn_mfma_f32_32x32x16_bf16(wh, xh, acc[mb], 0, 0, 0);
      acc[mb] = __builtin_amdgcn_mfma_f32_32x32x16_bf16(wh, xlo, acc[mb], 0, 0, 0);
      acc[mb] = __builtin_amdgcn_mfma_f32_32x32x16_bf16(wl, xh, acc[mb], 0, 0, 0);
    }
  }

  char* Qw = ws + Q_OFF + (size_t)n * (4096 * 64 * 2);
  char* Kw = ws + K_OFF + (size_t)n * (4096 * 64 * 2);
  unsigned short* Vw = (unsigned short*)(ws + V_OFF) + (size_t)n * 128 * 4096;

  if (wid < 2) {
    const float* bb = wid ? b2 : b1;
    float slope = wid ? a2[0] : a1[0];
    float scl = wid ? 1.0f : L2E;       // fold softmax log2e into Q
#pragma unroll
    for (int mb = 0; mb < 2; ++mb)
#pragma unroll
      for (int reg = 0; reg < 16; ++reg) {
        int row = mb * 32 + (reg & 3) + 8 * (reg >> 2) + 4 * hi;
        float y = acc[mb][reg] + bb[row];
        y = fmaxf(y, 0.f) + slope * fminf(y, 0.f);
        tl[wid][row][l31] = y * scl;
      }
  } else {
    float slope = aa[0];
#pragma unroll
    for (int mb = 0; mb < 2; ++mb)
#pragma unroll
      for (int reg = 0; reg < 16; ++reg) {
        int dv = (wid - 2) * 64 + mb * 32 + (reg & 3) + 8 * (reg >> 2) + 4 * hi;
        float y = acc[mb][reg] + ba[dv];
        y = fmaxf(y, 0.f) + slope * fminf(y, 0.f);
        Vw[(size_t)dv * 4096 + sb + l31] = f2bf(y);
      }
  }
  __syncthreads();
  if (wid < 2) {   // LDS-transposed, coalesced bf16 store of Q/K [s][64]
    char* Og = wid ? Kw : Qw;
#pragma unroll
    for (int it = 0; it < 4; ++it) {
      int sl = (lane >> 3) + it * 8;
      unsigned short u[8];
#pragma unroll
      for (int i = 0; i < 8; ++i) u[i] = f2bf(tl[wid][(lane & 7) * 8 + i][sl]);
      u32x4 pv;
      pv.x = ((unsigned)u[1] << 16) | u[0]; pv.y = ((unsigned)u[3] << 16) | u[2];
      pv.z = ((unsigned)u[5] << 16) | u[4]; pv.w = ((unsigned)u[7] << 16) | u[6];
      *(u32x4*)(Og + (size_t)(sb + sl) * 128 + (lane & 7) * 16) = pv;
    }
  }
}

// --------------------------- kernel 2: flash attention ----------------------
// 1024 blocks: bid = ((batch*32+qt)<<3)|split -> split==XCD (bid%8).
// Block = 4 waves * 32 q = 128 q; kv range = split*512..+512 (8 tiles of 64).
// LDS 48KB -> 3 blocks/CU -> 3 waves/SIMD.
__global__ __launch_bounds__(256, 3) void attn_kernel(char* __restrict__ ws) {
  int bid = blockIdx.x;
  int split = bid & 7;
  int qt = (bid >> 3) & 31;
  int batch = bid >> 8;
  int tid = threadIdx.x;
  int wid = tid >> 6, lane = tid & 63, l31 = lane & 31, hi = lane >> 5;

  const char* Qb = ws + Q_OFF + (size_t)batch * (4096 * 64 * 2);
  const char* Kb = ws + K_OFF + (size_t)batch * (4096 * 64 * 2);
  const char* Vb = ws + V_OFF + (size_t)batch * (128 * 4096 * 2);

  __shared__ char kbuf[2][64 * 128];    // [k][64d] bf16, XOR-swizzled slots
  __shared__ char vbuf[2][128 * 128];   // [dv][64k] bf16, XOR-swizzled slots

  int q0 = qt * 128 + wid * 32;

  bf16x8 qf[4];                         // Q B-frags: Q[q0+l31][16*d0 + 8*hi + j]
#pragma unroll
  for (int d0 = 0; d0 < 4; ++d0)
    qf[d0] = *(const bf16x8*)(Qb + (size_t)(q0 + l31) * 128 + d0 * 32 + hi * 16);

  f32x16 oacc[4];
#pragma unroll
  for (int i = 0; i < 4; ++i) oacc[i] = 0.f;
  float den = 0.f;

  int t0 = split * 8;                   // absolute 64-kv tile index base

  auto stage = [&](int b, int tile) {
    int kv0 = tile * 64;
#pragma unroll
    for (int i = 0; i < 2; ++i) {       // K: 8KB
      int base = wid * 2048 + i * 1024;
      int L = base + (lane << 4);
      int r = L >> 7, sl = (L >> 4) & 7;
      const char* src = Kb + (size_t)(kv0 + r) * 128 + ((sl ^ (r & 7)) << 4);
      gld_lds16(src, &kbuf[b][base]);
    }
#pragma unroll
    for (int i = 0; i < 4; ++i) {       // V: 16KB
      int base = wid * 4096 + i * 1024;
      int L = base + (lane << 4);
      int r = L >> 7, sl = (L >> 4) & 7;
      const char* src = Vb + (size_t)r * 8192 + kv0 * 2 + ((sl ^ (r & 7)) << 4);
      gld_lds16(src, &vbuf[b][base]);
    }
  };

  stage(0, t0);
  __syncthreads();
  int cur = 0;

  for (int t = 0; t < 8; ++t) {
    if (t + 1 < 8) stage(cur ^ 1, t0 + t + 1);

    // S^T[k][q] = K·Q^T  (q = l31; k = 32kb + (reg&3)+8*(reg>>2)+4*hi)
    f32x16 sacc[2];
    sacc[0] = 0.f; sacc[1] = 0.f;
    __builtin_amdgcn_s_setprio(1);
#pragma unroll
    for (int kb = 0; kb < 2; ++kb) {
      int r = kb * 32 + l31;
#pragma unroll
      for (int d0 = 0; d0 < 4; ++d0) {
        bf16x8 kf = *(const bf16x8*)(
            &kbuf[cur][r * 128 + (((d0 * 2 + hi) ^ (r & 7)) << 4)]);
        sacc[kb] = __builtin_amdgcn_mfma_f32_32x32x16_bf16(kf, qf[d0],
                                                           sacc[kb], 0, 0, 0);
      }
    }
    __builtin_amdgcn_s_setprio(0);

    // p = exp2(s) (Q pre-scaled by log2e), unnormalized; fused pack to bf16
    unsigned pk[2][8];
#pragma unroll
    for (int kb = 0; kb < 2; ++kb)
#pragma unroll
      for (int m = 0; m < 8; ++m) {
        float e0 = __builtin_amdgcn_exp2f(sacc[kb][2 * m]);
        float e1 = __builtin_amdgcn_exp2f(sacc[kb][2 * m + 1]);
        den += e0 + e1;
        bf16x2 bp = { (__bf16)e0, (__bf16)e1 };
        pk[kb][m] = __builtin_bit_cast(unsigned, bp);
      }

    // PV: O^T[dv][q] += V^T · P^T ; P^T B-frags via permlane32_swap
#pragma unroll
    for (int kc = 0; kc < 4; ++kc) {
      const int kb = kc >> 1, bs = (kc & 1) * 4;
      u32x2 r0 = __builtin_amdgcn_permlane32_swap(pk[kb][bs + 0], pk[kb][bs + 2],
                                                  false, false);
      u32x2 r1 = __builtin_amdgcn_permlane32_swap(pk[kb][bs + 1], pk[kb][bs + 3],
                                                  false, false);
      u32x4 pu = {r0.x, r1.x, r0.y, r1.y};
      bf16x8 pf = __builtin_bit_cast(bf16x8, pu);
      __builtin_amdgcn_s_setprio(1);
#pragma unroll
      for (int dvb = 0; dvb < 4; ++dvb) {
        int r = dvb * 32 + l31;
        bf16x8 vf = *(const bf16x8*)(
            &vbuf[cur][r * 128 + (((kc * 2 + hi) ^ (r & 7)) << 4)]);
        oacc[dvb] = __builtin_amdgcn_mfma_f32_32x32x16_bf16(vf, pf,
                                                            oacc[dvb], 0, 0, 0);
      }
      __builtin_amdgcn_s_setprio(0);
    }

    __syncthreads();
    cur ^= 1;
  }

  // write numerator partials (bf16) + denominator (f32)
  unsigned short* OPu = (unsigned short*)(ws + OP_OFF) +
                        (size_t)((batch * 32 + qt) * 8 + split) * 128 * 128;
  int qloc = wid * 32 + l31;
#pragma unroll
  for (int dvb = 0; dvb < 4; ++dvb)
#pragma unroll
    for (int reg = 0; reg < 16; ++reg) {
      int dv = dvb * 32 + (reg & 3) + 8 * (reg >> 2) + 4 * hi;
      OPu[dv * 128 + qloc] = f2bf(oacc[dvb][reg]);
    }
  float dtot = den + __shfl_xor(den, 32, 64);
  if (hi == 0) {
    float* DEN = (float*)(ws + DEN_OFF) +
                 (size_t)((batch * 32 + qt) * 8 + split) * 128;
    DEN[qloc] = dtot;
  }
}

// --------------------------- kernel 3: combine splits -----------------------
__global__ __launch_bounds__(256) void combine_kernel(const char* __restrict__ ws,
                                                      float* __restrict__ out) {
  int idx = blockIdx.x * 256 + threadIdx.x;  // 2^21 outputs [n][c][s]
  int n = idx >> 19;
  int dv = (idx >> 12) & 127;
  int s = idx & 4095;
  int qt = s >> 7, ql = s & 127;
  const unsigned short* OPu = (const unsigned short*)(ws + OP_OFF);
  const float* DEN = (const float*)(ws + DEN_OFF);
  size_t pb = (size_t)((n * 32 + qt) * 8);
  float num = 0.f, den = 0.f;
#pragma unroll
  for (int h = 0; h < 8; ++h) {
    num += bf2f(OPu[(pb + h) * 16384 + (size_t)dv * 128 + ql]);
    den += DEN[(pb + h) * 128 + ql];
  }
  out[idx] = num / den;
}

// ---------------------------------------------------------------------------
extern "C" void kernel_launch(void* const* d_in, const int* in_sizes, int n_in,
                              void* d_out, int out_size, void* d_ws, size_t ws_size,
                              hipStream_t stream) {
  (void)in_sizes; (void)n_in; (void)out_size; (void)ws_size;
  const float* x  = (const float*)d_in[0];
  const float* w1 = (const float*)d_in[1];
  const float* b1 = (const float*)d_in[2];
  const float* a1 = (const float*)d_in[3];
  const float* w2 = (const float*)d_in[4];
  const float* b2 = (const float*)d_in[5];
  const float* a2 = (const float*)d_in[6];
  const float* wa = (const float*)d_in[7];
  const float* ba = (const float*)d_in[8];
  const float* aa = (const float*)d_in[9];
  char* ws = (char*)d_ws;
  float* out = (float*)d_out;

  wcast_kernel<<<dim3(32), dim3(256), 0, stream>>>(w1, w2, wa, ws);
  conv_kernel<<<dim3(512), dim3(256), 0, stream>>>(x, ws, b1, a1, b2, a2, ba, aa);
  attn_kernel<<<dim3(1024), dim3(256), 0, stream>>>(ws);
  combine_kernel<<<dim3(8192), dim3(256), 0, stream>>>(ws, out);
}

// Round 5
// 64.135 us; speedup vs baseline: 1.1610x; 1.0080x over previous
//
#include <hip/hip_runtime.h>
#include <hip/hip_bf16.h>
#include <stdint.h>

// ---------------------------------------------------------------------------
// MultiScaleAttention: x[4,128,4096] -> 3x conv1x1+PReLU -> attention -> out
//   conv (fused transpose): Q = e1^T * log2e [n][s][64], K = e2^T [n][s][64],
//   V^T = asm [n][128][4096] (bf16). Split-bf16 (hi+lo) MFMA for fp32 accuracy.
//   attn: S^T = K Q^T (mfma 32x32x16, swapped), p = exp2(S^T) unnormalized,
//   O^T[dv][q] = V^T P^T; num (bf16) + den (f32) partials over 8 kv-splits.
//   KVBLK=32, LDS 24KB, 4 blocks/CU (grid 1024 = 4x256 exactly).
// ---------------------------------------------------------------------------

typedef float   f32x16 __attribute__((ext_vector_type(16)));
typedef __bf16  bf16x8 __attribute__((ext_vector_type(8)));
typedef __bf16  bf16x2 __attribute__((ext_vector_type(2)));
typedef unsigned int u32x4 __attribute__((ext_vector_type(4)));
typedef unsigned int u32x2 __attribute__((ext_vector_type(2)));

#define L2E 1.4426950408889634f

// workspace layout (bytes); ws_size ~268MB
#define Q_OFF   (0u)                          // [4][4096][64] bf16 = 2MB
#define K_OFF   (2u << 20)                    // [4][4096][64] bf16 = 2MB
#define V_OFF   (4u << 20)                    // [4][128][4096] bf16 = 4MB
#define DEN_OFF (8u << 20)                    // [4][32][8][128] f32 = 512KB
#define WH_OFF  ((8u << 20) + (1u << 19))     // W hi bf16 [256][128] = 64KB
#define WL_OFF  (WH_OFF + (1u << 16))
#define OP_OFF  (9u << 20)                    // num bf16 [4][32][8][128][128] = 33.5MB

__device__ inline unsigned short f2bf(float f) {
  unsigned u = __builtin_bit_cast(unsigned, f);
  return (unsigned short)((u + 0x7FFFu + ((u >> 16) & 1u)) >> 16);  // RNE
}
__device__ inline float bf2f(unsigned short h) {
  unsigned u = ((unsigned)h) << 16;
  return __builtin_bit_cast(float, u);
}

__device__ inline void gld_lds16(const void* g, void* l) {
  __builtin_amdgcn_global_load_lds(
      (const __attribute__((address_space(1))) unsigned*)g,
      (__attribute__((address_space(3))) unsigned*)l, 16, 0, 0);
}

// --------------------------- kernel 0: cast weights ------------------------
__global__ void wcast_kernel(const float* __restrict__ w1, const float* __restrict__ w2,
                             const float* __restrict__ wa, char* __restrict__ ws) {
  int idx = blockIdx.x * 256 + threadIdx.x;   // 32 blocks
  unsigned short* WH = (unsigned short*)(ws + WH_OFF);
  unsigned short* WL = (unsigned short*)(ws + WL_OFF);
#pragma unroll
  for (int r = 0; r < 4; ++r) {
    int i = r * 8192 + idx;                   // 0..32767
    int oc = i >> 7, c = i & 127;
    float v = oc < 64 ? w1[oc * 128 + c]
            : (oc < 128 ? w2[(oc - 64) * 128 + c] : wa[(oc - 128) * 128 + c]);
    unsigned short h = f2bf(v);
    WH[i] = h;
    WL[i] = f2bf(v - bf2f(h));
  }
}

// ------- kernel 1: conv1x1 + bias + PReLU -> Q,K,V (fused x transpose) ------
// 512 blocks = 4n * 128 s-tiles(32). Waves: 0->Q(*L2E), 1->K, 2,3->V.
// x tile staged in LDS [128c][36 pad] f32; B-frags built in-register (hi/lo).
__global__ __launch_bounds__(256) void conv_kernel(
    const float* __restrict__ x, char* __restrict__ ws,
    const float* __restrict__ b1, const float* __restrict__ a1,
    const float* __restrict__ b2, const float* __restrict__ a2,
    const float* __restrict__ ba, const float* __restrict__ aa) {
  int bid = blockIdx.x;
  int n = bid >> 7, st = bid & 127;
  int sb = st * 32;
  int tid = threadIdx.x;
  int wid = tid >> 6, lane = tid & 63, l31 = lane & 31, hi = lane >> 5;

  __shared__ float xl[128][36];         // stride 36 words: b128-aligned, 2-way banks
  __shared__ float tl[2][64][33];

  const float* xb = x + (size_t)n * 128 * 4096;
#pragma unroll
  for (int it = 0; it < 4; ++it) {      // load 128x32 f32 tile, transposed store
    int flat4 = tid + 256 * it;
    int c = flat4 >> 3, s4 = flat4 & 7;
    float4 v = *(const float4*)(xb + (size_t)c * 4096 + sb + s4 * 4);
    *(float4*)&xl[c][s4 * 4] = v;
  }
  __syncthreads();

  const char* WH = ws + WH_OFF;
  const char* WL = ws + WL_OFF;
  int oc0 = wid * 64;

  f32x16 acc[2];
  acc[0] = 0.f; acc[1] = 0.f;
#pragma unroll
  for (int c0 = 0; c0 < 8; ++c0) {
    // B-frag: x^T[s=l31][k = c0*16 + hi*8 + j], hi/lo split in-register
    __bf16 eh[8], el[8];
#pragma unroll
    for (int j = 0; j < 8; ++j) {
      float v = xl[c0 * 16 + hi * 8 + j][l31];
      __bf16 h = (__bf16)v;
      eh[j] = h;
      el[j] = (__bf16)(v - (float)h);
    }
    bf16x8 xh = {eh[0], eh[1], eh[2], eh[3], eh[4], eh[5], eh[6], eh[7]};
    bf16x8 xlo = {el[0], el[1], el[2], el[3], el[4], el[5], el[6], el[7]};
#pragma unroll
    for (int mb = 0; mb < 2; ++mb) {
      size_t wo = (size_t)(oc0 + mb * 32 + l31) * 256 + c0 * 32 + hi * 16;
      bf16x8 wh = *(const bf16x8*)(WH + wo);
      bf16x8 wl = *(const bf16x8*)(WL + wo);
      acc[mb] = __builtin_amdgcn_mfma_f32_32x32x16_bf16(wh, xh, acc[mb], 0, 0, 0);
      acc[mb] = __builtin_amdgcn_mfma_f32_32x32x16_bf16(wh, xlo, acc[mb], 0, 0, 0);
      acc[mb] = __builtin_amdgcn_mfma_f32_32x32x16_bf16(wl, xh, acc[mb], 0, 0, 0);
    }
  }

  char* Qw = ws + Q_OFF + (size_t)n * (4096 * 64 * 2);
  char* Kw = ws + K_OFF + (size_t)n * (4096 * 64 * 2);
  unsigned short* Vw = (unsigned short*)(ws + V_OFF) + (size_t)n * 128 * 4096;

  if (wid < 2) {
    const float* bb = wid ? b2 : b1;
    float slope = wid ? a2[0] : a1[0];
    float scl = wid ? 1.0f : L2E;       // fold softmax log2e into Q
#pragma unroll
    for (int mb = 0; mb < 2; ++mb)
#pragma unroll
      for (int reg = 0; reg < 16; ++reg) {
        int row = mb * 32 + (reg & 3) + 8 * (reg >> 2) + 4 * hi;
        float y = acc[mb][reg] + bb[row];
        y = fmaxf(y, 0.f) + slope * fminf(y, 0.f);
        tl[wid][row][l31] = y * scl;
      }
  } else {
    float slope = aa[0];
#pragma unroll
    for (int mb = 0; mb < 2; ++mb)
#pragma unroll
      for (int reg = 0; reg < 16; ++reg) {
        int dv = (wid - 2) * 64 + mb * 32 + (reg & 3) + 8 * (reg >> 2) + 4 * hi;
        float y = acc[mb][reg] + ba[dv];
        y = fmaxf(y, 0.f) + slope * fminf(y, 0.f);
        Vw[(size_t)dv * 4096 + sb + l31] = f2bf(y);
      }
  }
  __syncthreads();
  if (wid < 2) {   // LDS-transposed, coalesced bf16 store of Q/K [s][64]
    char* Og = wid ? Kw : Qw;
#pragma unroll
    for (int it = 0; it < 4; ++it) {
      int sl = (lane >> 3) + it * 8;
      unsigned short u[8];
#pragma unroll
      for (int i = 0; i < 8; ++i) u[i] = f2bf(tl[wid][(lane & 7) * 8 + i][sl]);
      u32x4 pv;
      pv.x = ((unsigned)u[1] << 16) | u[0]; pv.y = ((unsigned)u[3] << 16) | u[2];
      pv.z = ((unsigned)u[5] << 16) | u[4]; pv.w = ((unsigned)u[7] << 16) | u[6];
      *(u32x4*)(Og + (size_t)(sb + sl) * 128 + (lane & 7) * 16) = pv;
    }
  }
}

// --------------------------- kernel 2: flash attention ----------------------
// 1024 blocks: bid = ((batch*32+qt)<<3)|split -> split==XCD (bid%8).
// Block = 4 waves * 32 q = 128 q; kv range = split*512..+512 (16 tiles of 32).
// LDS 24KB, ~124 VGPR -> 4 blocks/CU -> 4 independent waves/SIMD.
__global__ __launch_bounds__(256, 4) void attn_kernel(char* __restrict__ ws) {
  int bid = blockIdx.x;
  int split = bid & 7;
  int qt = (bid >> 3) & 31;
  int batch = bid >> 8;
  int tid = threadIdx.x;
  int wid = tid >> 6, lane = tid & 63, l31 = lane & 31, hi = lane >> 5;

  const char* Qb = ws + Q_OFF + (size_t)batch * (4096 * 64 * 2);
  const char* Kb = ws + K_OFF + (size_t)batch * (4096 * 64 * 2);
  const char* Vb = ws + V_OFF + (size_t)batch * (128 * 4096 * 2);

  __shared__ char kbuf[2][32 * 128];    // [k][64d] bf16, XOR-swz slots (4KB ea)
  __shared__ char vbuf[2][128 * 64];    // [dv][32k] bf16, XOR-swz slots (8KB ea)

  int q0 = qt * 128 + wid * 32;

  bf16x8 qf[4];                         // Q B-frags: Q[q0+l31][16*d0 + 8*hi + j]
#pragma unroll
  for (int d0 = 0; d0 < 4; ++d0)
    qf[d0] = *(const bf16x8*)(Qb + (size_t)(q0 + l31) * 128 + d0 * 32 + hi * 16);

  f32x16 oacc[4];
#pragma unroll
  for (int i = 0; i < 4; ++i) oacc[i] = 0.f;
  float den = 0.f;

  int t0 = split * 16;                  // absolute 32-kv tile index base

  auto stage = [&](int b, int tile) {
    int kv0 = tile * 32;
    {                                   // K: 4KB, 1 instr/wave
      int base = wid * 1024;
      int L = base + (lane << 4);
      int r = L >> 7, sl = (L >> 4) & 7;
      const char* src = Kb + (size_t)(kv0 + r) * 128 + ((sl ^ (r & 7)) << 4);
      gld_lds16(src, &kbuf[b][base]);
    }
#pragma unroll
    for (int i = 0; i < 2; ++i) {       // V: 8KB, 2 instr/wave
      int base = wid * 2048 + i * 1024;
      int L = base + (lane << 4);
      int r = L >> 6, sl = (L >> 4) & 3;
      const char* src = Vb + (size_t)r * 8192 + kv0 * 2 + ((sl ^ (r & 3)) << 4);
      gld_lds16(src, &vbuf[b][base]);
    }
  };

  stage(0, t0);
  __syncthreads();
  int cur = 0;

  for (int t = 0; t < 16; ++t) {
    if (t + 1 < 16) stage(cur ^ 1, t0 + t + 1);

    // S^T[k][q] = K·Q^T  (q = l31; k = (reg&3)+8*(reg>>2)+4*hi)
    f32x16 sacc;
    sacc = 0.f;
    __builtin_amdgcn_s_setprio(1);
#pragma unroll
    for (int d0 = 0; d0 < 4; ++d0) {
      int r = l31;
      bf16x8 kf = *(const bf16x8*)(
          &kbuf[cur][r * 128 + (((d0 * 2 + hi) ^ (r & 7)) << 4)]);
      sacc = __builtin_amdgcn_mfma_f32_32x32x16_bf16(kf, qf[d0], sacc, 0, 0, 0);
    }
    __builtin_amdgcn_s_setprio(0);

    // p = exp2(s) (Q pre-scaled by log2e), unnormalized; fused pack to bf16
    unsigned pk[8];
#pragma unroll
    for (int m = 0; m < 8; ++m) {
      float e0 = __builtin_amdgcn_exp2f(sacc[2 * m]);
      float e1 = __builtin_amdgcn_exp2f(sacc[2 * m + 1]);
      den += e0 + e1;
      bf16x2 bp = { (__bf16)e0, (__bf16)e1 };
      pk[m] = __builtin_bit_cast(unsigned, bp);
    }

    // PV: O^T[dv][q] += V^T · P^T ; P^T B-frags via permlane32_swap
#pragma unroll
    for (int kc = 0; kc < 2; ++kc) {
      const int bs = kc * 4;
      u32x2 r0 = __builtin_amdgcn_permlane32_swap(pk[bs + 0], pk[bs + 2],
                                                  false, false);
      u32x2 r1 = __builtin_amdgcn_permlane32_swap(pk[bs + 1], pk[bs + 3],
                                                  false, false);
      u32x4 pu = {r0.x, r1.x, r0.y, r1.y};
      bf16x8 pf = __builtin_bit_cast(bf16x8, pu);
      __builtin_amdgcn_s_setprio(1);
#pragma unroll
      for (int dvb = 0; dvb < 4; ++dvb) {
        int r = dvb * 32 + l31;
        bf16x8 vf = *(const bf16x8*)(
            &vbuf[cur][r * 64 + (((kc * 2 + hi) ^ (r & 3)) << 4)]);
        oacc[dvb] = __builtin_amdgcn_mfma_f32_32x32x16_bf16(vf, pf,
                                                            oacc[dvb], 0, 0, 0);
      }
      __builtin_amdgcn_s_setprio(0);
    }

    __syncthreads();
    cur ^= 1;
  }

  // write numerator partials (bf16) + denominator (f32)
  unsigned short* OPu = (unsigned short*)(ws + OP_OFF) +
                        (size_t)((batch * 32 + qt) * 8 + split) * 128 * 128;
  int qloc = wid * 32 + l31;
#pragma unroll
  for (int dvb = 0; dvb < 4; ++dvb)
#pragma unroll
    for (int reg = 0; reg < 16; ++reg) {
      int dv = dvb * 32 + (reg & 3) + 8 * (reg >> 2) + 4 * hi;
      OPu[dv * 128 + qloc] = f2bf(oacc[dvb][reg]);
    }
  float dtot = den + __shfl_xor(den, 32, 64);
  if (hi == 0) {
    float* DEN = (float*)(ws + DEN_OFF) +
                 (size_t)((batch * 32 + qt) * 8 + split) * 128;
    DEN[qloc] = dtot;
  }
}

// --------------------------- kernel 3: combine splits -----------------------
__global__ __launch_bounds__(256) void combine_kernel(const char* __restrict__ ws,
                                                      float* __restrict__ out) {
  int idx = blockIdx.x * 256 + threadIdx.x;  // 2^21 outputs [n][c][s]
  int n = idx >> 19;
  int dv = (idx >> 12) & 127;
  int s = idx & 4095;
  int qt = s >> 7, ql = s & 127;
  const unsigned short* OPu = (const unsigned short*)(ws + OP_OFF);
  const float* DEN = (const float*)(ws + DEN_OFF);
  size_t pb = (size_t)((n * 32 + qt) * 8);
  float num = 0.f, den = 0.f;
#pragma unroll
  for (int h = 0; h < 8; ++h) {
    num += bf2f(OPu[(pb + h) * 16384 + (size_t)dv * 128 + ql]);
    den += DEN[(pb + h) * 128 + ql];
  }
  out[idx] = num / den;
}

// ---------------------------------------------------------------------------
extern "C" void kernel_launch(void* const* d_in, const int* in_sizes, int n_in,
                              void* d_out, int out_size, void* d_ws, size_t ws_size,
                              hipStream_t stream) {
  (void)in_sizes; (void)n_in; (void)out_size; (void)ws_size;
  const float* x  = (const float*)d_in[0];
  const float* w1 = (const float*)d_in[1];
  const float* b1 = (const float*)d_in[2];
  const float* a1 = (const float*)d_in[3];
  const float* w2 = (const float*)d_in[4];
  const float* b2 = (const float*)d_in[5];
  const float* a2 = (const float*)d_in[6];
  const float* wa = (const float*)d_in[7];
  const float* ba = (const float*)d_in[8];
  const float* aa = (const float*)d_in[9];
  char* ws = (char*)d_ws;
  float* out = (float*)d_out;

  wcast_kernel<<<dim3(32), dim3(256), 0, stream>>>(w1, w2, wa, ws);
  conv_kernel<<<dim3(512), dim3(256), 0, stream>>>(x, ws, b1, a1, b2, a2, ba, aa);
  attn_kernel<<<dim3(1024), dim3(256), 0, stream>>>(ws);
  combine_kernel<<<dim3(8192), dim3(256), 0, stream>>>(ws, out);
}